// Round 2
// baseline (281.367 us; speedup 1.0000x reference)
//
#include <hip/hip_runtime.h>
#include <cfloat>

// MultiDepthLimitedMSELoss: per-row greedy matching + masked MSE -> scalar mean.
// Row-parallel, memory-bound (268 MB read). One float accumulator in d_ws.

#define DVALS 8

__global__ __launch_bounds__(256) void mdmse_match_kernel(
    const float* __restrict__ outputs,
    const float* __restrict__ targets,
    float* __restrict__ accum,
    int n_rows)
{
    int tid = blockIdx.x * blockDim.x + threadIdx.x;
    int stride = gridDim.x * blockDim.x;

    float local = 0.0f;

    for (int row = tid; row < n_rows; row += stride) {
        // 32 B contiguous per row: two float4 loads each.
        const float4* op = reinterpret_cast<const float4*>(outputs + (size_t)row * DVALS);
        const float4* tp = reinterpret_cast<const float4*>(targets + (size_t)row * DVALS);
        float4 o0 = op[0], o1 = op[1];
        float4 t0 = tp[0], t1 = tp[1];

        float o[DVALS] = {o0.x, o0.y, o0.z, o0.w, o1.x, o1.y, o1.z, o1.w};
        float t[DVALS] = {t0.x, t0.y, t0.z, t0.w, t1.x, t1.y, t1.z, t1.w};

        // Working copy for knockout. All indexing below is compile-time
        // (fully unrolled) so everything stays in VGPRs (no scratch).
        float cpy[DVALS];
#pragma unroll
        for (int j = 0; j < DVALS; ++j) cpy[j] = o[j];

#pragma unroll
        for (int i = 0; i < DVALS; ++i) {
            float tc = t[i];
            // argmin_j |cpy[j] - tc|, first-index tie-break (matches jnp.argmin)
            float bd = FLT_MAX;
            int bi = -1;
#pragma unroll
            for (int j = 0; j < DVALS; ++j) {
                float d = fabsf(cpy[j] - tc);
                bool better = d < bd;       // strict < -> first occurrence wins
                bd = better ? d : bd;
                bi = better ? j : bi;
            }
            // Select matched value and knock it out, all with static indices.
            float bestv = 0.0f;
#pragma unroll
            for (int j = 0; j < DVALS; ++j) {
                bool hit = (bi == j);
                bestv = hit ? cpy[j] : bestv;
                cpy[j] = hit ? FLT_MAX : cpy[j];
            }
            // seltarget = (t != 0) ? t : matched_output  => diff 0 when t == 0
            float diff = (tc != 0.0f) ? (bestv - tc) : 0.0f;
            local = fmaf(diff, diff, local);
        }
    }

    // wave-64 butterfly reduce
#pragma unroll
    for (int off = 32; off > 0; off >>= 1)
        local += __shfl_down(local, off, 64);

    __shared__ float wsum[4];  // 256 threads / 64 lanes
    int lane = threadIdx.x & 63;
    int wid  = threadIdx.x >> 6;
    if (lane == 0) wsum[wid] = local;
    __syncthreads();

    if (threadIdx.x == 0) {
        float s = wsum[0] + wsum[1] + wsum[2] + wsum[3];
        atomicAdd(accum, s);   // ~2048 atomics total, negligible contention
    }
}

__global__ void mdmse_finalize_kernel(const float* __restrict__ accum,
                                      float* __restrict__ out,
                                      float inv_count)
{
    out[0] = accum[0] * inv_count;
}

extern "C" void kernel_launch(void* const* d_in, const int* in_sizes, int n_in,
                              void* d_out, int out_size, void* d_ws, size_t ws_size,
                              hipStream_t stream)
{
    const float* outputs = (const float*)d_in[0];
    const float* targets = (const float*)d_in[1];
    float* out = (float*)d_out;
    float* accum = (float*)d_ws;

    const int n_rows = in_sizes[0] / DVALS;

    // d_ws is poisoned 0xAA before every launch -> zero the accumulator.
    hipMemsetAsync(accum, 0, sizeof(float), stream);

    const int block = 256;
    int grid = 2048;  // ~8 rows/thread grid-stride; scheduler headroom (G11)
    int max_grid = (n_rows + block - 1) / block;
    if (grid > max_grid) grid = max_grid;

    mdmse_match_kernel<<<grid, block, 0, stream>>>(outputs, targets, accum, n_rows);

    const float inv_count = 1.0f / ((float)n_rows * (float)DVALS);
    mdmse_finalize_kernel<<<1, 1, 0, stream>>>(accum, out, inv_count);
}

// Round 4
// 280.802 us; speedup vs baseline: 1.0020x; 1.0020x over previous
//
#include <hip/hip_runtime.h>
#include <cfloat>

// MultiDepthLimitedMSELoss: per-row greedy matching + masked MSE -> scalar mean.
// R3: latency-bound fix — 4 rows/thread with all loads issued upfront (8 KB
// MLP/wave), and bd^2 trick (|bestv-tc| == bd exactly, so the bestv select
// pass is dead). Block partials scaled by 1/(N*D) and atomically added
// straight into d_out (memset to 0 first; graph-safe).

#define DVALS 8
#define ROWS_PER_THREAD 4

__global__ __launch_bounds__(256) void mdmse_match_kernel(
    const float* __restrict__ outputs,
    const float* __restrict__ targets,
    float* __restrict__ out,
    int n_rows,
    float inv_count)
{
    int tid = blockIdx.x * blockDim.x + threadIdx.x;
    int stride = gridDim.x * blockDim.x;

    float local = 0.0f;

    for (int base = tid; base < n_rows; base += stride * ROWS_PER_THREAD) {
        // Issue all global loads first: 8 x dwordx4 in flight per thread.
        float4 ov[ROWS_PER_THREAD][2];
        float4 tv4[ROWS_PER_THREAD][2];
        bool valid[ROWS_PER_THREAD];
#pragma unroll
        for (int k = 0; k < ROWS_PER_THREAD; ++k) {
            int r = base + k * stride;
            valid[k] = (r < n_rows);
            if (valid[k]) {
                const float4* op = reinterpret_cast<const float4*>(outputs + (size_t)r * DVALS);
                const float4* tp = reinterpret_cast<const float4*>(targets + (size_t)r * DVALS);
                ov[k][0] = op[0]; ov[k][1] = op[1];
                tv4[k][0] = tp[0]; tv4[k][1] = tp[1];
            }
        }

#pragma unroll
        for (int k = 0; k < ROWS_PER_THREAD; ++k) {
            if (!valid[k]) continue;
            // All indexing compile-time (full unroll) -> stays in VGPRs.
            float cpy[DVALS] = {ov[k][0].x, ov[k][0].y, ov[k][0].z, ov[k][0].w,
                                ov[k][1].x, ov[k][1].y, ov[k][1].z, ov[k][1].w};
            float t[DVALS]   = {tv4[k][0].x, tv4[k][0].y, tv4[k][0].z, tv4[k][0].w,
                                tv4[k][1].x, tv4[k][1].y, tv4[k][1].z, tv4[k][1].w};

#pragma unroll
            for (int i = 0; i < DVALS; ++i) {
                float tc = t[i];
                // argmin_j |cpy[j]-tc|, strict < -> first index wins (jnp.argmin)
                float bd = FLT_MAX;
                int bi = -1;
#pragma unroll
                for (int j = 0; j < DVALS; ++j) {
                    float d = fabsf(cpy[j] - tc);
                    bool better = d < bd;
                    bd = better ? d : bd;
                    bi = better ? j : bi;
                }
                // knockout only (matched VALUE is not needed: |bestv-tc| == bd,
                // and bd*bd is bit-identical to (bestv-tc)^2)
#pragma unroll
                for (int j = 0; j < DVALS; ++j)
                    cpy[j] = (bi == j) ? FLT_MAX : cpy[j];

                // t==0 -> seltarget = output -> term vanishes
                float c = (tc != 0.0f) ? bd : 0.0f;
                local = fmaf(c, c, local);
            }
        }
    }

    // wave-64 butterfly reduce
#pragma unroll
    for (int off = 32; off > 0; off >>= 1)
        local += __shfl_down(local, off, 64);

    __shared__ float wsum[4];  // 256 threads / 64 lanes
    int lane = threadIdx.x & 63;
    int wid  = threadIdx.x >> 6;
    if (lane == 0) wsum[wid] = local;
    __syncthreads();

    if (threadIdx.x == 0) {
        float s = wsum[0] + wsum[1] + wsum[2] + wsum[3];
        atomicAdd(out, s * inv_count);  // ~4096 atomics, negligible contention
    }
}

extern "C" void kernel_launch(void* const* d_in, const int* in_sizes, int n_in,
                              void* d_out, int out_size, void* d_ws, size_t ws_size,
                              hipStream_t stream)
{
    const float* outputs = (const float*)d_in[0];
    const float* targets = (const float*)d_in[1];
    float* out = (float*)d_out;

    const int n_rows = in_sizes[0] / DVALS;

    // d_out is re-poisoned 0xAA before every timed launch -> zero it ourselves.
    hipMemsetAsync(out, 0, sizeof(float), stream);

    const int block = 256;
    long long want = ((long long)n_rows + block * ROWS_PER_THREAD - 1) /
                     (block * ROWS_PER_THREAD);
    int grid = (int)want;            // N=4.19M -> 4096 blocks, one outer iter
    if (grid < 1) grid = 1;

    const float inv_count = 1.0f / ((float)n_rows * (float)DVALS);
    mdmse_match_kernel<<<grid, block, 0, stream>>>(outputs, targets, out,
                                                   n_rows, inv_count);
}